// Round 2
// baseline (234.944 us; speedup 1.0000x reference)
//
#include <hip/hip_runtime.h>
#include <hip/hip_cooperative_groups.h>

namespace cg = cooperative_groups;

// MLPEdgePredictor: score[e] = h[src[e]] @ W_u^T + h[dst[e]] @ W_v^T + b
// Factored: pq[n] = {h[n]@Wu0 + b0, h[n]@Wu1 + b1, h[n]@Wv0, h[n]@Wv1}  (per node)
//           out[e] = {pq[src].x + pq[dst].z, pq[src].y + pq[dst].w}
// 51M MACs + 1.6MB L2-resident gather instead of 820M MACs + 1.6GB gather.
// Single cooperative kernel: phase1 (projection) -> grid.sync -> phase2 (gather),
// saving a dispatch + full-device drain, and keeping pq hot in L2.

#define DIM 128
#define GRID_BLOCKS 1024   // 4 blocks/CU co-residency @ 256 CUs — safe for cooperative launch
#define BLOCK_THREADS 256

__global__ __launch_bounds__(BLOCK_THREADS)
void fused_edge_mlp(const float* __restrict__ h,
                    const float* __restrict__ W,
                    const float* __restrict__ b,
                    const int* __restrict__ src,
                    const int* __restrict__ dst,
                    float4* __restrict__ pq,
                    float* __restrict__ out,
                    int n_nodes, int n_edges) {
    // ---- Phase 1: per-node projection (half-wave = 32 lanes per node) ----
    int lane = threadIdx.x & 63;
    int half = lane >> 5;                         // node slot within wave
    int j    = lane & 31;                         // float4 slot within 128-dim row
    int gwave = (blockIdx.x * BLOCK_THREADS + threadIdx.x) >> 6;  // 0..4095
    const int nodes_per_sweep = GRID_BLOCKS * (BLOCK_THREADS / 64) * 2;  // 8192

    // W is (2, 256) row-major: row o = [W_u[o][0:128] | W_v[o][0:128]]
    const float4* W4 = (const float4*)W;
    float4 wu0 = W4[j];
    float4 wv0 = W4[32 + j];
    float4 wu1 = W4[64 + j];
    float4 wv1 = W4[96 + j];
    float b0 = b[0], b1 = b[1];

    for (int node = gwave * 2 + half; node < n_nodes; node += nodes_per_sweep) {
        float4 hv = ((const float4*)(h + (size_t)node * DIM))[j];

        float su0 = hv.x*wu0.x + hv.y*wu0.y + hv.z*wu0.z + hv.w*wu0.w;
        float su1 = hv.x*wu1.x + hv.y*wu1.y + hv.z*wu1.z + hv.w*wu1.w;
        float sv0 = hv.x*wv0.x + hv.y*wv0.y + hv.z*wv0.z + hv.w*wv0.w;
        float sv1 = hv.x*wv1.x + hv.y*wv1.y + hv.z*wv1.z + hv.w*wv1.w;

        #pragma unroll
        for (int m = 16; m >= 1; m >>= 1) {       // stays within 32-lane half
            su0 += __shfl_xor(su0, m);
            su1 += __shfl_xor(su1, m);
            sv0 += __shfl_xor(sv0, m);
            sv1 += __shfl_xor(sv1, m);
        }

        if (j == 0)
            pq[node] = make_float4(su0 + b0, su1 + b1, sv0, sv1);
    }

    cg::this_grid().sync();

    // ---- Phase 2: per-edge gather+add, 2 edges/thread, float4 stores ----
    int n_thr = (n_edges + 1) / 2;
    const int stride = GRID_BLOCKS * BLOCK_THREADS;
    for (int t = blockIdx.x * BLOCK_THREADS + threadIdx.x; t < n_thr; t += stride) {
        int e0 = t * 2;
        if (e0 + 1 < n_edges) {
            int2 s = ((const int2*)src)[t];
            int2 d = ((const int2*)dst)[t];
            float4 a0 = pq[s.x];
            float4 c0 = pq[d.x];
            float4 a1 = pq[s.y];
            float4 c1 = pq[d.y];
            float4 o;
            o.x = a0.x + c0.z;
            o.y = a0.y + c0.w;
            o.z = a1.x + c1.z;
            o.w = a1.y + c1.w;
            ((float4*)out)[t] = o;
        } else {                                   // odd tail (not hit for 1.6M edges)
            int s = src[e0], d = dst[e0];
            float4 a = pq[s];
            float4 c = pq[d];
            out[(size_t)e0 * 2 + 0] = a.x + c.z;
            out[(size_t)e0 * 2 + 1] = a.y + c.w;
        }
    }
}

extern "C" void kernel_launch(void* const* d_in, const int* in_sizes, int n_in,
                              void* d_out, int out_size, void* d_ws, size_t ws_size,
                              hipStream_t stream) {
    const float* h   = (const float*)d_in[0];
    const int*   src = (const int*)d_in[1];
    const int*   dst = (const int*)d_in[2];
    const float* W   = (const float*)d_in[3];
    const float* b   = (const float*)d_in[4];
    float*       out = (float*)d_out;

    int n_nodes = in_sizes[0] / DIM;
    int n_edges = in_sizes[1];

    float4* pq = (float4*)d_ws;    // n_nodes * 16 B = 1.6 MB scratch

    void* args[] = {(void*)&h, (void*)&W, (void*)&b, (void*)&src, (void*)&dst,
                    (void*)&pq, (void*)&out, (void*)&n_nodes, (void*)&n_edges};
    hipLaunchCooperativeKernel((void*)fused_edge_mlp,
                               dim3(GRID_BLOCKS), dim3(BLOCK_THREADS),
                               args, 0, stream);
}

// Round 4
// 122.441 us; speedup vs baseline: 1.9188x; 1.9188x over previous
//
#include <hip/hip_runtime.h>

// MLPEdgePredictor: score[e] = h[src[e]] @ W_u^T + h[dst[e]] @ W_v^T + b
// Factored: pq[n] = {h[n]@Wu0 + b0, h[n]@Wu1 + b1, h[n]@Wv0, h[n]@Wv1}  (per node)
//           out[e] = {pq[src].x + pq[dst].z, pq[src].y + pq[dst].w}
// 51M MACs + 1.6MB L2-resident gather instead of 820M MACs + 1.6GB gather.
//
// Two plain dispatches. Round-2 lesson: a cooperative grid.sync() costs ~120us
// on this workload (cross-XCD spin barrier) vs ~4us for a stream dispatch
// boundary — never again.
// Round-3 lesson: __builtin_nontemporal_* needs clang ext_vector_type, not
// the HIP_vector_type float4 struct.

#define DIM 128

typedef float fvec4 __attribute__((ext_vector_type(4)));
typedef int   ivec4 __attribute__((ext_vector_type(4)));

// Kernel 1: per-node projection. Half-wave (32 lanes) per node: lane j loads
// float4 h[node][4j..4j+3] (coalesced 512B per half-wave), dots against the 4
// weight fragments, butterfly-reduces over 32 lanes (masks <=16 never cross
// the 32-lane half on wave64).
__global__ __launch_bounds__(256) void node_project(const float* __restrict__ h,
                                                    const float* __restrict__ W,
                                                    const float* __restrict__ b,
                                                    fvec4* __restrict__ pq,
                                                    int n_nodes) {
    int gtid = blockIdx.x * blockDim.x + threadIdx.x;
    int wave = gtid >> 6;
    int lane = threadIdx.x & 63;
    int half = lane >> 5;          // which node within the wave
    int j    = lane & 31;          // float4 slot within the 128-dim row
    int node = wave * 2 + half;

    // W is (2, 256) row-major: row o = [W_u[o][0:128] | W_v[o][0:128]]
    const fvec4* W4 = (const fvec4*)W;   // 2 rows x 64 fvec4
    fvec4 wu0 = W4[j];             // W[0][4j..]
    fvec4 wv0 = W4[32 + j];        // W[0][128+4j..]
    fvec4 wu1 = W4[64 + j];        // W[1][4j..]
    fvec4 wv1 = W4[96 + j];        // W[1][128+4j..]

    fvec4 hv = (fvec4)0.f;
    if (node < n_nodes) {
        // streaming read, no reuse — keep it out of L2's way
        const fvec4* hp = (const fvec4*)(h + (size_t)node * DIM) + j;
        hv = __builtin_nontemporal_load(hp);
    }

    float su0 = hv.x*wu0.x + hv.y*wu0.y + hv.z*wu0.z + hv.w*wu0.w;
    float su1 = hv.x*wu1.x + hv.y*wu1.y + hv.z*wu1.z + hv.w*wu1.w;
    float sv0 = hv.x*wv0.x + hv.y*wv0.y + hv.z*wv0.z + hv.w*wv0.w;
    float sv1 = hv.x*wv1.x + hv.y*wv1.y + hv.z*wv1.z + hv.w*wv1.w;

    #pragma unroll
    for (int m = 16; m >= 1; m >>= 1) {
        su0 += __shfl_xor(su0, m);
        su1 += __shfl_xor(su1, m);
        sv0 += __shfl_xor(sv0, m);
        sv1 += __shfl_xor(sv1, m);
    }

    if (j == 0 && node < n_nodes) {
        // bias folded into src-side entries; pq stays L2-resident for kernel 2
        fvec4 r;
        r.x = su0 + b[0];
        r.y = su1 + b[1];
        r.z = sv0;
        r.w = sv1;
        pq[node] = r;
    }
}

// Kernel 2: per-edge gather+add. 4 edges/thread: int4 index loads (16B),
// two float4 output stores (nontemporal — written once, never read).
// pq table is 1.6MB -> L2-resident gather.
__global__ __launch_bounds__(256) void edge_gather(const int* __restrict__ src,
                                                   const int* __restrict__ dst,
                                                   const fvec4* __restrict__ pq,
                                                   float* __restrict__ out,
                                                   int n_edges) {
    int t = blockIdx.x * blockDim.x + threadIdx.x;
    int e0 = t * 4;
    if (e0 + 3 < n_edges) {
        ivec4 s = ((const ivec4*)src)[t];
        ivec4 d = ((const ivec4*)dst)[t];
        fvec4 a0 = pq[s.x], c0 = pq[d.x];
        fvec4 a1 = pq[s.y], c1 = pq[d.y];
        fvec4 a2 = pq[s.z], c2 = pq[d.z];
        fvec4 a3 = pq[s.w], c3 = pq[d.w];
        fvec4 o01, o23;
        o01.x = a0.x + c0.z;  o01.y = a0.y + c0.w;
        o01.z = a1.x + c1.z;  o01.w = a1.y + c1.w;
        o23.x = a2.x + c2.z;  o23.y = a2.y + c2.w;
        o23.z = a3.x + c3.z;  o23.w = a3.y + c3.w;
        fvec4* op = (fvec4*)out + t * 2;
        __builtin_nontemporal_store(o01, op);
        __builtin_nontemporal_store(o23, op + 1);
    } else {
        for (int e = e0; e < n_edges; ++e) {      // tail (not hit for 1.6M edges)
            int s = src[e], d = dst[e];
            fvec4 a = pq[s];
            fvec4 c = pq[d];
            out[(size_t)e * 2 + 0] = a.x + c.z;
            out[(size_t)e * 2 + 1] = a.y + c.w;
        }
    }
}

extern "C" void kernel_launch(void* const* d_in, const int* in_sizes, int n_in,
                              void* d_out, int out_size, void* d_ws, size_t ws_size,
                              hipStream_t stream) {
    const float* h   = (const float*)d_in[0];
    const int*   src = (const int*)d_in[1];
    const int*   dst = (const int*)d_in[2];
    const float* W   = (const float*)d_in[3];
    const float* b   = (const float*)d_in[4];
    float*       out = (float*)d_out;

    int n_nodes = in_sizes[0] / DIM;
    int n_edges = in_sizes[1];

    fvec4* pq = (fvec4*)d_ws;      // n_nodes * 16 B = 1.6 MB scratch

    // 8 nodes per 256-thread block (2 nodes/wave x 4 waves)
    int blocks1 = (n_nodes + 7) / 8;
    node_project<<<blocks1, 256, 0, stream>>>(h, W, b, pq, n_nodes);

    int n_threads = (n_edges + 3) / 4;
    int blocks2 = (n_threads + 255) / 256;
    edge_gather<<<blocks2, 256, 0, stream>>>(src, dst, pq, out, n_edges);
}

// Round 5
// 117.166 us; speedup vs baseline: 2.0052x; 1.0450x over previous
//
#include <hip/hip_runtime.h>

// MLPEdgePredictor: score[e] = h[src[e]] @ W_u^T + h[dst[e]] @ W_v^T + b
// Factored: pq[n] = {h[n]@Wu0 + b0, h[n]@Wu1 + b1, h[n]@Wv0, h[n]@Wv1}  (per node)
//           out[e] = {pq[src].x + pq[dst].z, pq[src].y + pq[dst].w}
// 51M MACs + 1.6MB L2-resident gather instead of 820M MACs + 1.6GB gather.
//
// Final form = round-1 structure (best measured 118.5us end-to-end):
//  - two plain dispatches; round-2 showed cooperative grid.sync() costs ~120us
//    (cross-XCD spin barrier) vs ~4us for a stream dispatch boundary.
//  - no nontemporal hints; round-4 showed them neutral-to-negative here.
//  - my two kernels total ~13-15us (compulsory 77MB @ ~6.3TB/s); the rest of
//    dur_us is the harness's 268MB ws re-poison floor (fills at ~81% HBM peak).

#define DIM 128

// Kernel 1: per-node projection. Half-wave (32 lanes) per node: lane j loads
// float4 h[node][4j..4j+3] (fully coalesced 512B per half-wave), dots against
// 4 weight fragments, butterfly-reduces over 32 lanes (masks <=16 never cross
// the 32-lane boundary, so default-width __shfl_xor is safe on wave64).
__global__ __launch_bounds__(256) void node_project(const float* __restrict__ h,
                                                    const float* __restrict__ W,
                                                    const float* __restrict__ b,
                                                    float4* __restrict__ pq,
                                                    int n_nodes) {
    int gtid = blockIdx.x * blockDim.x + threadIdx.x;
    int wave = gtid >> 6;
    int lane = threadIdx.x & 63;
    int half = lane >> 5;          // which node within the wave
    int j    = lane & 31;          // float4 slot within the 128-dim row
    int node = wave * 2 + half;

    // W is (2, 256) row-major: row o = [W_u[o][0:128] | W_v[o][0:128]]
    const float4* W4 = (const float4*)W;   // 2 rows x 64 float4
    float4 wu0 = W4[j];            // W[0][4j..]
    float4 wv0 = W4[32 + j];       // W[0][128+4j..]
    float4 wu1 = W4[64 + j];       // W[1][4j..]
    float4 wv1 = W4[96 + j];       // W[1][128+4j..]

    float4 hv = make_float4(0.f, 0.f, 0.f, 0.f);
    if (node < n_nodes)
        hv = ((const float4*)(h + (size_t)node * DIM))[j];

    float su0 = hv.x*wu0.x + hv.y*wu0.y + hv.z*wu0.z + hv.w*wu0.w;
    float su1 = hv.x*wu1.x + hv.y*wu1.y + hv.z*wu1.z + hv.w*wu1.w;
    float sv0 = hv.x*wv0.x + hv.y*wv0.y + hv.z*wv0.z + hv.w*wv0.w;
    float sv1 = hv.x*wv1.x + hv.y*wv1.y + hv.z*wv1.z + hv.w*wv1.w;

    #pragma unroll
    for (int m = 16; m >= 1; m >>= 1) {
        su0 += __shfl_xor(su0, m);
        su1 += __shfl_xor(su1, m);
        sv0 += __shfl_xor(sv0, m);
        sv1 += __shfl_xor(sv1, m);
    }

    if (j == 0 && node < n_nodes) {
        // fold bias into the src-side entries so the gather kernel adds nothing extra
        pq[node] = make_float4(su0 + b[0], su1 + b[1], sv0, sv1);
    }
}

// Kernel 2: per-edge gather+add. 2 edges/thread: int2 index loads (8B),
// float4 output store (16B). pq table is 1.6MB -> L2-resident gather.
__global__ __launch_bounds__(256) void edge_gather(const int* __restrict__ src,
                                                   const int* __restrict__ dst,
                                                   const float4* __restrict__ pq,
                                                   float* __restrict__ out,
                                                   int n_edges) {
    int t = blockIdx.x * blockDim.x + threadIdx.x;
    int e0 = t * 2;
    if (e0 + 1 < n_edges) {
        int2 s = ((const int2*)src)[t];
        int2 d = ((const int2*)dst)[t];
        float4 a0 = pq[s.x];
        float4 c0 = pq[d.x];
        float4 a1 = pq[s.y];
        float4 c1 = pq[d.y];
        float4 o;
        o.x = a0.x + c0.z;
        o.y = a0.y + c0.w;
        o.z = a1.x + c1.z;
        o.w = a1.y + c1.w;
        ((float4*)out)[t] = o;
    } else if (e0 < n_edges) {       // odd tail (not hit for 1.6M edges)
        int s = src[e0], d = dst[e0];
        float4 a = pq[s];
        float4 c = pq[d];
        out[(size_t)e0 * 2 + 0] = a.x + c.z;
        out[(size_t)e0 * 2 + 1] = a.y + c.w;
    }
}

extern "C" void kernel_launch(void* const* d_in, const int* in_sizes, int n_in,
                              void* d_out, int out_size, void* d_ws, size_t ws_size,
                              hipStream_t stream) {
    const float* h   = (const float*)d_in[0];
    const int*   src = (const int*)d_in[1];
    const int*   dst = (const int*)d_in[2];
    const float* W   = (const float*)d_in[3];
    const float* b   = (const float*)d_in[4];
    float*       out = (float*)d_out;

    int n_nodes = in_sizes[0] / DIM;
    int n_edges = in_sizes[1];

    float4* pq = (float4*)d_ws;    // n_nodes * 16 B = 1.6 MB scratch

    // 8 nodes per 256-thread block (2 nodes/wave x 4 waves)
    int blocks1 = (n_nodes + 7) / 8;
    node_project<<<blocks1, 256, 0, stream>>>(h, W, b, pq, n_nodes);

    int n_threads = (n_edges + 1) / 2;
    int blocks2 = (n_threads + 255) / 256;
    edge_gather<<<blocks2, 256, 0, stream>>>(src, dst, pq, out, n_edges);
}